// Round 1
// baseline (306.770 us; speedup 1.0000x reference)
//
#include <hip/hip_runtime.h>
#include <hip/hip_bf16.h>
#include <cstdint>
#include <cstddef>

// MHA forward: B=2, T=2048, D=1024, H=16, dk=64. fp32 in/out, bf16 MFMA internal.
#define B_  2
#define T_  2048
#define D_  1024
#define H_  16
#define DK_ 64

typedef __hip_bfloat16 bf16;
typedef __bf16 bf16x8 __attribute__((ext_vector_type(8)));  // MFMA A/B frag (4 VGPRs)
typedef float  f32x4  __attribute__((ext_vector_type(4)));  // MFMA C/D frag

#define MFMA16(a, b, c) __builtin_amdgcn_mfma_f32_16x16x32_bf16((a), (b), (c), 0, 0, 0)

__device__ static inline void gld_lds16(const void* g, void* l) {
  // async global->LDS, 16B per lane; LDS dest is wave-uniform base + lane*16
  __builtin_amdgcn_global_load_lds((const __attribute__((address_space(1))) void*)g,
                                   (__attribute__((address_space(3))) void*)l, 16, 0, 0);
}

// ---------------- pack: x fp32 -> bf16 ----------------
__global__ __launch_bounds__(256) void pack_x_kernel(const float* __restrict__ x,
                                                     bf16* __restrict__ xb) {
  const int i = blockIdx.x * 256 + threadIdx.x;  // exactly 1M threads, 4 elems each
  const float4 v = reinterpret_cast<const float4*>(x)[i];
  union { ushort4 u; bf16 h[4]; } c;
  c.h[0] = __float2bfloat16(v.x);
  c.h[1] = __float2bfloat16(v.y);
  c.h[2] = __float2bfloat16(v.z);
  c.h[3] = __float2bfloat16(v.w);
  reinterpret_cast<ushort4*>(xb)[i] = c.u;
}

// ---------------- pack: W (D,D) fp32 row-major [k][n] -> bf16 transposed [n][k] ----------------
__global__ __launch_bounds__(256) void pack_w_kernel(const float* __restrict__ Wq,
                                                     const float* __restrict__ Wk,
                                                     const float* __restrict__ Wv,
                                                     const float* __restrict__ Wo,
                                                     bf16* __restrict__ Wt,    // [3072][1024]
                                                     bf16* __restrict__ Wot) { // [1024][1024]
  __shared__ bf16 t[64][65];  // +1 pad breaks bank conflicts on transposed read
  const int bid  = blockIdx.x;
  const int mat  = bid >> 8;       // 0..3 : Wq,Wk,Wv,Wo
  const int tile = bid & 255;      // 16x16 tiles of 64x64
  const int tr = tile >> 4, tc = tile & 15;
  const float* W = (mat == 0) ? Wq : (mat == 1) ? Wk : (mat == 2) ? Wv : Wo;
  const int tid = threadIdx.x;
#pragma unroll
  for (int i = 0; i < 16; ++i) {
    const int idx = i * 256 + tid;
    const int r = idx >> 6, c = idx & 63;
    t[r][c] = __float2bfloat16(W[(size_t)(tr * 64 + r) * D_ + tc * 64 + c]);
  }
  __syncthreads();
  bf16* dst = (mat == 3) ? Wot : (Wt + (size_t)mat * D_ * D_);
#pragma unroll
  for (int i = 0; i < 16; ++i) {
    const int idx = i * 256 + tid;
    const int n = idx >> 6, k = idx & 63;
    dst[(size_t)(tc * 64 + n) * D_ + tr * 64 + k] = t[k][n];
  }
}

// ---------------- 128x128 bf16 GEMM, BK=32, 4 waves (2x2 of 64x64) ----------------
// A: [M][K] row-major bf16.  Bt: [N][K] row-major bf16 (i.e. B transposed).
// MODE 0: QKV epilogue -> Qb/Kb [BH][T][64], Vt [BH][64][T], + bias (per 1024-col segment)
// MODE 1: out epilogue -> fp32 [M][1024] + bias0
template <int MODE>
__global__ __launch_bounds__(256, 2) void gemm128_kernel(
    const bf16* __restrict__ A, const bf16* __restrict__ Bt,
    const float* __restrict__ bias0, const float* __restrict__ bias1,
    const float* __restrict__ bias2,
    bf16* __restrict__ Qb, bf16* __restrict__ Kb, bf16* __restrict__ Vt,
    float* __restrict__ outp, int K) {
  __shared__ bf16 As[128 * 32];
  __shared__ bf16 Bs[128 * 32];
  const int tid  = threadIdx.x;
  const int lane = tid & 63, wid = tid >> 6;
  const int wr = wid >> 1, wc = wid & 1;
  const int l15 = lane & 15, lhi = lane >> 4;
  const int mbase = blockIdx.y * 128, nbase = blockIdx.x * 128;

  f32x4 acc[4][4] = {};

  const int r0  = tid >> 2;        // staged row for chunk p=0 (p=1 is +64)
  const int kc0 = (tid & 3) * 8;   // k offset within BK
  char* AsB = (char*)As;
  char* BsB = (char*)Bs;

  for (int kt = 0; kt < K; kt += 32) {
    gld_lds16(A  + (size_t)(mbase + r0)      * K + kt + kc0, AsB + wid * 1024);
    gld_lds16(A  + (size_t)(mbase + 64 + r0) * K + kt + kc0, AsB + 4096 + wid * 1024);
    gld_lds16(Bt + (size_t)(nbase + r0)      * K + kt + kc0, BsB + wid * 1024);
    gld_lds16(Bt + (size_t)(nbase + 64 + r0) * K + kt + kc0, BsB + 4096 + wid * 1024);
    __syncthreads();  // compiler drains vmcnt before barrier

    bf16x8 af[4], bfv[4];
#pragma unroll
    for (int m = 0; m < 4; ++m)
      af[m] = *reinterpret_cast<const bf16x8*>(&As[(wr * 64 + m * 16 + l15) * 32 + lhi * 8]);
#pragma unroll
    for (int n = 0; n < 4; ++n)
      bfv[n] = *reinterpret_cast<const bf16x8*>(&Bs[(wc * 64 + n * 16 + l15) * 32 + lhi * 8]);
#pragma unroll
    for (int m = 0; m < 4; ++m)
#pragma unroll
      for (int n = 0; n < 4; ++n)
        acc[m][n] = MFMA16(af[m], bfv[n], acc[m][n]);
    __syncthreads();
  }

  // epilogue: D layout col = lane&15, row = (lane>>4)*4 + j
#pragma unroll
  for (int n = 0; n < 4; ++n) {
    const int col = nbase + wc * 64 + n * 16 + l15;
    if (MODE == 0) {
      const int seg  = col >> 10;      // 0=Q 1=K 2=V (uniform per block: N tiles are 128-wide)
      const int ncol = col & 1023;
      const float* bias = (seg == 0) ? bias0 : (seg == 1) ? bias1 : bias2;
      const float bv_ = bias[ncol];
      const int h = ncol >> 6, dk = ncol & 63;
#pragma unroll
      for (int m = 0; m < 4; ++m) {
#pragma unroll
        for (int j = 0; j < 4; ++j) {
          const int row = mbase + wr * 64 + m * 16 + lhi * 4 + j;
          const int b = row >> 11, t = row & 2047;
          const int bh = b * H_ + h;
          const bf16 hv = __float2bfloat16(acc[m][n][j] + bv_);
          if (seg == 0)      Qb[((size_t)bh * T_ + t) * DK_ + dk] = hv;
          else if (seg == 1) Kb[((size_t)bh * T_ + t) * DK_ + dk] = hv;
          else               Vt[((size_t)bh * DK_ + dk) * T_ + t] = hv;  // transposed V
        }
      }
    } else {
      const float bv_ = bias0[col];
#pragma unroll
      for (int m = 0; m < 4; ++m)
#pragma unroll
        for (int j = 0; j < 4; ++j) {
          const int row = mbase + wr * 64 + m * 16 + lhi * 4 + j;
          outp[(size_t)row * D_ + col] = acc[m][n][j] + bv_;
        }
    }
  }
}

// ---------------- flash attention (causal), 4 independent waves/block, 16 q-rows/wave ----------------
// Q,K: [BH][T][64] bf16.  Vt: [BH][64][T] bf16.  Mg: [B*T][D] bf16 (merged heads).
__global__ __launch_bounds__(256, 2) void attn_kernel(const bf16* __restrict__ Q,
                                                      const bf16* __restrict__ Kg,
                                                      const bf16* __restrict__ Vt,
                                                      bf16* __restrict__ Mg) {
  __shared__ bf16 plds[4][16 * 40];  // per-wave P transpose buffer, padded row=40 (bank spread)
  const int tid = threadIdx.x, lane = tid & 63, wid = tid >> 6;
  const int l15 = lane & 15, lhi = lane >> 4;
  const int bh = blockIdx.x >> 5;   // 32 q-tiles of 64 per (b,h)
  const int qt = blockIdx.x & 31;
  const int qbase = qt * 64 + wid * 16;
  const int b = bh >> 4, h = bh & 15;

  const bf16* Qp = Q  + (size_t)bh * T_ * DK_;
  const bf16* Kp = Kg + (size_t)bh * T_ * DK_;
  const bf16* Vp = Vt + (size_t)bh * DK_ * T_;

  const int qrow = qbase + l15;
  const bf16x8 qf0 = *reinterpret_cast<const bf16x8*>(&Qp[(size_t)qrow * DK_ + lhi * 8]);
  const bf16x8 qf1 = *reinterpret_cast<const bf16x8*>(&Qp[(size_t)qrow * DK_ + 32 + lhi * 8]);

  f32x4 o[4] = {};
  float mrow[4] = {-1e30f, -1e30f, -1e30f, -1e30f};
  float lrow[4] = {0.f, 0.f, 0.f, 0.f};

  bf16* pw = plds[wid];
  const int qmax = qbase + 15;
  for (int kv0 = 0; kv0 <= qmax; kv0 += 32) {
    // S = Q K^T for 16 q-rows x 32 kv-cols (two 16x16 MFMA tiles, K-dim 64)
    f32x4 s0 = {}, s1 = {};
    const bf16x8 k00 = *reinterpret_cast<const bf16x8*>(&Kp[(size_t)(kv0 + l15) * DK_ + lhi * 8]);
    const bf16x8 k01 = *reinterpret_cast<const bf16x8*>(&Kp[(size_t)(kv0 + l15) * DK_ + 32 + lhi * 8]);
    const bf16x8 k10 = *reinterpret_cast<const bf16x8*>(&Kp[(size_t)(kv0 + 16 + l15) * DK_ + lhi * 8]);
    const bf16x8 k11 = *reinterpret_cast<const bf16x8*>(&Kp[(size_t)(kv0 + 16 + l15) * DK_ + 32 + lhi * 8]);
    s0 = MFMA16(qf0, k00, s0);
    s0 = MFMA16(qf1, k01, s0);
    s1 = MFMA16(qf0, k10, s1);
    s1 = MFMA16(qf1, k11, s1);

    // scale + causal mask. S layout: col = kv0(+16) + l15, row = qbase + lhi*4 + j
    const int c0 = kv0 + l15, c1 = kv0 + 16 + l15;
    float mx[4];
#pragma unroll
    for (int j = 0; j < 4; ++j) {
      const int r = qbase + lhi * 4 + j;
      const float v0 = (c0 <= r) ? s0[j] * 0.125f : -1e30f;
      const float v1 = (c1 <= r) ? s1[j] * 0.125f : -1e30f;
      s0[j] = v0; s1[j] = v1;
      mx[j] = fmaxf(v0, v1);
    }
    // row max across the 16 lanes holding this row's columns
#pragma unroll
    for (int off = 8; off >= 1; off >>= 1)
#pragma unroll
      for (int j = 0; j < 4; ++j)
        mx[j] = fmaxf(mx[j], __shfl_xor(mx[j], off, 64));

    float sc[4], rs[4];
#pragma unroll
    for (int j = 0; j < 4; ++j) {
      const float mn = fmaxf(mrow[j], mx[j]);
      sc[j] = __expf(mrow[j] - mn);
      mrow[j] = mn;
      const float p0 = __expf(s0[j] - mn);
      const float p1 = __expf(s1[j] - mn);
      s0[j] = p0; s1[j] = p1;
      rs[j] = p0 + p1;
    }
#pragma unroll
    for (int off = 8; off >= 1; off >>= 1)
#pragma unroll
      for (int j = 0; j < 4; ++j)
        rs[j] += __shfl_xor(rs[j], off, 64);

#pragma unroll
    for (int j = 0; j < 4; ++j) {
      lrow[j] = lrow[j] * sc[j] + rs[j];
      o[0][j] *= sc[j]; o[1][j] *= sc[j]; o[2][j] *= sc[j]; o[3][j] *= sc[j];
    }

    // transpose P via per-wave LDS (S layout -> A-frag layout)
#pragma unroll
    for (int j = 0; j < 4; ++j) {
      pw[(lhi * 4 + j) * 40 + l15]      = __float2bfloat16(s0[j]);
      pw[(lhi * 4 + j) * 40 + 16 + l15] = __float2bfloat16(s1[j]);
    }
    asm volatile("s_waitcnt lgkmcnt(0)" ::: "memory");  // wave-internal write->read fence
    const bf16x8 pf = *reinterpret_cast<const bf16x8*>(&pw[l15 * 40 + lhi * 8]);

    // O += P V : B-frag from transposed V is contiguous along kv
#pragma unroll
    for (int d = 0; d < 4; ++d) {
      const bf16x8 vf = *reinterpret_cast<const bf16x8*>(&Vp[(size_t)(d * 16 + l15) * T_ + kv0 + lhi * 8]);
      o[d] = MFMA16(pf, vf, o[d]);
    }
  }

#pragma unroll
  for (int j = 0; j < 4; ++j) {
    const float inv = 1.0f / lrow[j];
    const int t = qbase + lhi * 4 + j;
#pragma unroll
    for (int d = 0; d < 4; ++d)
      Mg[((size_t)b * T_ + t) * D_ + h * DK_ + d * 16 + l15] = __float2bfloat16(o[d][j] * inv);
  }
}

// ---------------- launch ----------------
extern "C" void kernel_launch(void* const* d_in, const int* in_sizes, int n_in,
                              void* d_out, int out_size, void* d_ws, size_t ws_size,
                              hipStream_t stream) {
  (void)in_sizes; (void)n_in; (void)out_size; (void)ws_size;
  const float* x  = (const float*)d_in[0];
  const float* Wq = (const float*)d_in[1];
  const float* bq = (const float*)d_in[2];
  const float* Wk = (const float*)d_in[3];
  const float* bk = (const float*)d_in[4];
  const float* Wv = (const float*)d_in[5];
  const float* bv = (const float*)d_in[6];
  const float* Wo = (const float*)d_in[7];
  const float* bo = (const float*)d_in[8];
  float* out = (float*)d_out;

  // workspace layout (40 MB): Mg aliases xb (xb dead after QKV GEMM, attn runs after)
  char* ws = (char*)d_ws;
  bf16* xb  = (bf16*)(ws);                       // 8 MB [4096][1024]
  bf16* Mg  = (bf16*)(ws);                       // 8 MB [4096][1024] (alias, written by attn)
  bf16* Wt  = (bf16*)(ws + (size_t)( 8u << 20)); // 6 MB [3072][1024] (Wq|Wk|Wv transposed)
  bf16* Wot = (bf16*)(ws + (size_t)(14u << 20)); // 2 MB [1024][1024] (Wo transposed)
  bf16* Qb  = (bf16*)(ws + (size_t)(16u << 20)); // 8 MB [32][2048][64]
  bf16* Kb  = (bf16*)(ws + (size_t)(24u << 20)); // 8 MB [32][2048][64]
  bf16* Vt  = (bf16*)(ws + (size_t)(32u << 20)); // 8 MB [32][64][2048]

  pack_x_kernel<<<4096, 256, 0, stream>>>(x, xb);
  pack_w_kernel<<<1024, 256, 0, stream>>>(Wq, Wk, Wv, Wo, Wt, Wot);
  // fused QKV: C[4096][3072] = xb @ [Wq|Wk|Wv]
  gemm128_kernel<0><<<dim3(24, 32), 256, 0, stream>>>(xb, Wt, bq, bk, bv, Qb, Kb, Vt, nullptr, 1024);
  attn_kernel<<<dim3(1024), 256, 0, stream>>>(Qb, Kb, Vt, Mg);
  // out[4096][1024] = Mg @ Wo + bo
  gemm128_kernel<1><<<dim3(8, 32), 256, 0, stream>>>(Mg, Wot, bo, nullptr, nullptr, nullptr, nullptr, nullptr, out, 1024);
}